// Round 1
// 617.193 us; speedup vs baseline: 1.0266x; 1.0266x over previous
//
#include <hip/hip_runtime.h>
#include <hip/hip_bf16.h>
#include <stdint.h>
#include <type_traits>

// Problem constants: B=256, T=512, D=300, H=128, 4H=512, C=6
#define NB 256
#define NT 512
#define ND 300
#define NH 128
#define NG 512
#define NC 6

typedef __attribute__((ext_vector_type(8))) short short8;
typedef __attribute__((ext_vector_type(4))) float f32x4;

static __device__ __forceinline__ float bf2f(unsigned int u) {
  return __builtin_bit_cast(float, (u & 0xffffu) << 16);
}
static __device__ __forceinline__ unsigned short f2bf(float f) {
  return __builtin_bit_cast(unsigned short, __float2bfloat16(f));
}
static __device__ __forceinline__ unsigned int packbf(float a, float b) {
  return (unsigned int)f2bf(a) | ((unsigned int)f2bf(b) << 16);
}
static __device__ __forceinline__ float ld1(const unsigned short* p) { return bf2f(*p); }
static __device__ __forceinline__ float ld1(const float* p) { return *p; }
static __device__ __forceinline__ void st1(unsigned short* p, float v) { *p = f2bf(v); }
static __device__ __forceinline__ void st1(float* p, float v) { *p = v; }

static __device__ __forceinline__ float sigmoid_fast(float x) {
  return __builtin_amdgcn_rcpf(1.f + __expf(-x));
}
static __device__ __forceinline__ float tanh_fast(float x) {
  return 1.f - 2.f * __builtin_amdgcn_rcpf(__expf(2.f * x) + 1.f);
}

// ---- staging loads: 4 K-elems -> 2 packed bf16 pairs ------------------------
static __device__ __forceinline__ uint2 load4bf_fast(const unsigned short* row, int k) {
  return *(const uint2*)(row + k);  // 8B-aligned (k%4==0, row stride 600B)
}
static __device__ __forceinline__ uint2 load4bf_fast(const float* row, int k) {
  float4 f = *(const float4*)(row + k);  // 16B-aligned (k%4==0, row stride 1200B)
  uint2 v;
  v.x = packbf(f.x, f.y);
  v.y = packbf(f.z, f.w);
  return v;
}
static __device__ __forceinline__ uint2 load4bf(const unsigned short* row, int k, int lim) {
  if (k + 3 < lim) return load4bf_fast(row, k);
  unsigned int e0 = (k + 0 < lim) ? row[k + 0] : 0;
  unsigned int e1 = (k + 1 < lim) ? row[k + 1] : 0;
  unsigned int e2 = (k + 2 < lim) ? row[k + 2] : 0;
  unsigned int e3 = (k + 3 < lim) ? row[k + 3] : 0;
  uint2 v;
  v.x = e0 | (e1 << 16);
  v.y = e2 | (e3 << 16);
  return v;
}
static __device__ __forceinline__ uint2 load4bf(const float* row, int k, int lim) {
  if (k + 3 < lim) return load4bf_fast(row, k);
  float f0 = (k + 0 < lim) ? row[k + 0] : 0.f;
  float f1 = (k + 1 < lim) ? row[k + 1] : 0.f;
  float f2 = (k + 2 < lim) ? row[k + 2] : 0.f;
  float f3 = (k + 3 < lim) ? row[k + 3] : 0.f;
  uint2 v;
  v.x = packbf(f0, f1);
  v.y = packbf(f2, f3);
  return v;
}

// ---------------------------------------------------------------------------
// Dtype detector (flag: 0 = bf16 inputs, 1 = fp32 inputs).
// ---------------------------------------------------------------------------
__global__ void detect_dtype(const unsigned short* __restrict__ X, int* __restrict__ flag) {
  __shared__ int cnt;
  if (threadIdx.x == 0) cnt = 0;
  __syncthreads();
  int c = 0;
  for (int i = threadIdx.x; i < 512; i += 64) {
    unsigned int u = X[i];
    unsigned int e = (u >> 7) & 0xffu;
    if (u == 0u || (e >= 97u && e <= 157u)) c++;
  }
  atomicAdd(&cnt, c);
  __syncthreads();
  if (threadIdx.x == 0) *flag = (cnt >= 448) ? 0 : 1;
}

// ---------------------------------------------------------------------------
// Phase 1: gx[m][n] = sum_k x[b,t,k] * W_ih[n][k]  + (bih[n]+bhh[n]).
//
// REWRITE (this round): the previous 128Mx64N kernel re-staged the same x
// tile from global memory once per N-strip (8x re-read = 1.26 GB, spilling
// the 4MB/XCD L2 -> L3 latency-bound staging, ~300us, half the wall clock).
// New structure: M-tile 64, FULL-K A staged ONCE into LDS (As[10][64][40],
// 50 KB, read-only afterwards -> x read from HBM exactly once). Only B
// (W_ih, 600 KB, L2-resident across all blocks) streams per 32-K chunk,
// double-buffered with ONE barrier per chunk and distance-2 register
// prefetch. 4 waves (2Mx2N), per wave 32Mx128N: acc[2][4], 8 MFMA + 6
// ds_read_b128 per chunk. LDS 70 KB -> 2 blocks/CU (LDS-bound, so VGPR
// pressure in the prologue is free). Grid = M/64 = 2048 blocks.
// HBM floor: x 157MB (f32) + gx 134MB (bf16) ~ 46us.
// ---------------------------------------------------------------------------
template <typename XT, typename GXT>
__global__ __launch_bounds__(256) void gx_gemm(const int* __restrict__ flag, int want,
                                               const XT* __restrict__ X,
                                               const XT* __restrict__ Wih,
                                               const XT* __restrict__ bih,
                                               const XT* __restrict__ bhh,
                                               const int* __restrict__ lengths,
                                               GXT* __restrict__ gx,
                                               int b_base, int t_base, int Tc) {
  if (*flag != want) return;
  const int mb = blockIdx.x;
  const int m0 = mb << 6;  // 64 rows per block
  const int bc = m0 / Tc;
  const int trel0 = m0 % Tc;
  const int b = b_base + bc;
  const int t0 = t_base + trel0;
  const int len = lengths[b];
  if (t0 >= len) return;

  // A: full K (10 chunks of 32), staged once. 40-pad => conflict-free b128
  // frag reads (row stride 80B = 20 dw; starts cover all 32 banks 2-way).
  __shared__ unsigned short As[10][64][40];  // 50 KB
  __shared__ unsigned short Bs[2][128][40];  // 20 KB, double-buffered

  const int tid = threadIdx.x;
  const int lane = tid & 63;
  const int wave = tid >> 6;
  const int wm = wave & 1;   // M strip of 32
  const int wn = wave >> 1;  // N strip of 64 (within 128-col pass)
  const int lq = lane >> 4;
  const int lr = lane & 15;

  // ---- Prologue: stage A (64 rows x 320 k) once --------------------------
  // rA = tid>>2 (0..63); each quad covers 32 k per chunk; per-call addresses
  // are quad-contiguous (16 floats / 64B per instruction).
  const int rA = tid >> 2;
  const int cA = (tid & 3) << 2;  // 0,4,8,12
  const XT* xrow = X + ((size_t)b * NT + t0 + rA) * ND;
  {
    uint2 a0[10], a1[10];
#pragma unroll
    for (int kc = 0; kc < 9; ++kc) {
      a0[kc] = load4bf_fast(xrow, kc * 32 + cA);
      a1[kc] = load4bf_fast(xrow, kc * 32 + 16 + cA);
    }
    a0[9] = load4bf(xrow, 288 + cA, ND);       // 288..303 masked at 300
    a1[9] = load4bf(xrow, 288 + 16 + cA, ND);  // 304..319 all masked
#pragma unroll
    for (int kc = 0; kc < 10; ++kc) {
      *(uint2*)&As[kc][rA][cA] = a0[kc];
      *(uint2*)&As[kc][rA][16 + cA] = a1[kc];
    }
  }

  // ---- B stream: 4 passes of 128 N-cols ----------------------------------
  // rB = tid>>1 (0..127); per chunk 16 k per thread; per-call addresses are
  // pair-contiguous (8 floats / 32B per lane-pair per instruction).
  const int rB = tid >> 1;
  const int cB = (tid & 1) << 2;  // 0 or 4; call g4 adds g4*8

  for (int nt = 0; nt < 4; ++nt) {
    const int n0 = nt << 7;
    const XT* wrow = Wih + (size_t)(n0 + rB) * ND;

    f32x4 acc[2][4];
#pragma unroll
    for (int i = 0; i < 2; ++i)
#pragma unroll
      for (int j = 0; j < 4; ++j) {
        f32x4 z = {0.f, 0.f, 0.f, 0.f};
        acc[i][j] = z;
      }

    // Register double-buffer: bv[p] holds chunk with parity p.
    uint2 bv[2][4];
#pragma unroll
    for (int g4 = 0; g4 < 4; ++g4) bv[0][g4] = load4bf_fast(wrow, cB + g4 * 8);
#pragma unroll
    for (int g4 = 0; g4 < 4; ++g4) bv[1][g4] = load4bf_fast(wrow, 32 + cB + g4 * 8);

    __syncthreads();  // prev pass readers done (also covers A staging, nt=0)
#pragma unroll
    for (int g4 = 0; g4 < 4; ++g4) *(uint2*)&Bs[0][rB][cB + g4 * 8] = bv[0][g4];
    __syncthreads();  // chunk 0 visible

#pragma unroll
    for (int kc = 0; kc < 10; ++kc) {
      const int bi = kc & 1;
      // stage chunk kc+1 into the other buffer (its last readers were at
      // kc-1, separated by the barrier at end of kc-1)
      if (kc < 9) {
#pragma unroll
        for (int g4 = 0; g4 < 4; ++g4)
          *(uint2*)&Bs[bi ^ 1][rB][cB + g4 * 8] = bv[bi ^ 1][g4];
      }
      // prefetch chunk kc+2 into the reg slot just retired (parity kc&1)
      if (kc < 8) {
        const int kn = (kc + 2) * 32;
        if (kc < 7) {
#pragma unroll
          for (int g4 = 0; g4 < 4; ++g4) bv[bi][g4] = load4bf_fast(wrow, kn + cB + g4 * 8);
        } else {  // chunk 9: 288..319 masked at 300
#pragma unroll
          for (int g4 = 0; g4 < 4; ++g4) bv[bi][g4] = load4bf(wrow, kn + cB + g4 * 8, ND);
        }
      }

      short8 af[2], bq[4];
#pragma unroll
      for (int tm = 0; tm < 2; ++tm)
        af[tm] = *(const short8*)&As[kc][wm * 32 + tm * 16 + lr][lq * 8];
#pragma unroll
      for (int tn = 0; tn < 4; ++tn)
        bq[tn] = *(const short8*)&Bs[bi][wn * 64 + tn * 16 + lr][lq * 8];
#pragma unroll
      for (int tm = 0; tm < 2; ++tm)
#pragma unroll
        for (int tn = 0; tn < 4; ++tn)
          acc[tm][tn] =
              __builtin_amdgcn_mfma_f32_16x16x32_bf16(af[tm], bq[tn], acc[tm][tn], 0, 0, 0);
      __syncthreads();
    }

    // Epilogue: add bias (bih+bhh) per output column, store.
    // C/D layout: col = lane&15, row = (lane>>4)*4 + reg
    float bias_c[4];
#pragma unroll
    for (int tn = 0; tn < 4; ++tn) {
      const int col = n0 + wn * 64 + tn * 16 + lr;
      bias_c[tn] = ld1(bih + col) + ld1(bhh + col);
    }
#pragma unroll
    for (int tm = 0; tm < 2; ++tm)
#pragma unroll
      for (int tn = 0; tn < 4; ++tn)
#pragma unroll
        for (int rg = 0; rg < 4; ++rg) {
          const int row = wm * 32 + tm * 16 + lq * 4 + rg;
          if (t0 + row < len) {
            const int col = n0 + wn * 64 + tn * 16 + lr;
            st1(gx + (size_t)(m0 + row) * NG + col, acc[tm][tn][rg] + bias_c[tn]);
          }
        }
  }
}

// ---------------------------------------------------------------------------
// Phase 2: per-batch recurrence via MFMA matvec. 8 waves; wave w owns units
// [16w,16w+16). A = W_hh fragments (4 gates x 4 k-chunks, 64 VGPRs).
// B = h broadcast to all 16 columns: 4 ds_read_b128/wave/step.
// Update: lane (q,m) handles ONLY unit u0+(m&3) (4x lane redundancy, no extra
// instructions): 4 gx loads + 12 cndmask acc-selects + 10 trans/lane/step.
// Bias pre-folded into gx. ONE barrier/step. waves_per_eu pinned to 2 so the
// 256-VGPR budget holds afr without spills (round-5 failure mode).
// ---------------------------------------------------------------------------
template <typename XT, typename GXT>
__global__ __launch_bounds__(512)
__attribute__((amdgpu_waves_per_eu(2, 2)))
void lstm_rec(const int* __restrict__ flag, int want,
              const GXT* __restrict__ gx,
              const XT* __restrict__ Whh,
              const XT* __restrict__ fcw,
              const XT* __restrict__ fcb,
              const int* __restrict__ lengths,
              XT* __restrict__ out,
              float* __restrict__ hstate,
              float* __restrict__ cstate,
              int b_base, int t_base, int Tc) {
  if (*flag != want) return;
  const int bc = blockIdx.x;
  const int b = b_base + bc;
  int len = lengths[b];
  if (len > NT) len = NT;
  if (len < 0) len = 0;
  const bool first = (t_base == 0);
  const bool last = (t_base + Tc >= NT);
  const int tend = (len < t_base + Tc) ? len : (t_base + Tc);
  if (!last && tend <= t_base) return;  // no steps; ws state untouched
  int nsteps = tend - t_base;
  if (nsteps < 0) nsteps = 0;

  const int tid = threadIdx.x;
  const int w8 = tid >> 6;         // wave: units [w8*16, w8*16+16)
  const int l = tid & 63;
  const int q = l >> 4;            // quad group
  const int m = l & 15;            // A-frag row select / D column id
  const int u0 = w8 * 16 + q * 4;  // first unit of this lane's D rows
  const int r = m & 3;             // unit handled by this lane
  const int u = u0 + r;

  __shared__ __align__(16) unsigned short hpk[2][NH];  // packed bf16 h, dbuf
  __shared__ __align__(16) float hf[NH];               // final h (FC epilogue)

  // A fragments: afr[g][c] = W_hh[g*128 + w8*16 + m][c*32 + q*8 .. +8]
  short8 afr[4][4];
#pragma unroll
  for (int g = 0; g < 4; ++g) {
    const int row = g * NH + w8 * 16 + m;
    if constexpr (std::is_same_v<XT, unsigned short>) {
#pragma unroll
      for (int c = 0; c < 4; ++c)
        afr[g][c] = *(const short8*)(Whh + (size_t)row * NH + c * 32 + q * 8);
    } else {
#pragma unroll
      for (int c = 0; c < 4; ++c) {
        const float* p = Whh + (size_t)row * NH + c * 32 + q * 8;
        float4 f0 = *(const float4*)p;
        float4 f1 = *(const float4*)(p + 4);
        union { unsigned int uu[4]; short8 s; } cv2;
        cv2.uu[0] = packbf(f0.x, f0.y);
        cv2.uu[1] = packbf(f0.z, f0.w);
        cv2.uu[2] = packbf(f1.x, f1.y);
        cv2.uu[3] = packbf(f1.z, f1.w);
        afr[g][c] = cv2.s;
      }
    }
  }

  float hcur = 0.f, ccur = 0.f;
  if (!first) {
    hcur = hstate[(size_t)bc * NH + u];
    ccur = cstate[(size_t)bc * NH + u];
  }
  if (m < 4) hpk[0][u] = f2bf(hcur);
  __syncthreads();

  // gx pointers for this lane's unit: 4 gates at offsets g*128
  const GXT* gp = gx + (size_t)bc * Tc * NG + u;
  const int lastidx = (nsteps > 0) ? nsteps - 1 : 0;
  float g_c[4], g_n[4];
#pragma unroll
  for (int g = 0; g < 4; ++g) {
    g_c[g] = ld1(gp + g * NH);                                 // idx 0
    g_n[g] = ld1(gp + (size_t)((1 < lastidx) ? 1 : lastidx) * NG + g * NH);  // idx min(1,last)
  }

  for (int s = 0; s < nsteps; ++s) {
    // prefetch step s+2 (clamped; clamped loads are valid, never consumed)
    int idx = s + 2;
    if (idx > lastidx) idx = lastidx;
    float g_f[4];
#pragma unroll
    for (int g = 0; g < 4; ++g) g_f[g] = ld1(gp + (size_t)idx * NG + g * NH);

    // B fragments: h[k] broadcast to all columns; k = c*32 + q*8 + j
    short8 bfr[4];
    const unsigned short* hrow = hpk[s & 1];
#pragma unroll
    for (int c = 0; c < 4; ++c) bfr[c] = *(const short8*)&hrow[c * 32 + q * 8];

    f32x4 acc[4];
#pragma unroll
    for (int g = 0; g < 4; ++g) {
      f32x4 z = {0.f, 0.f, 0.f, 0.f};
      acc[g] = z;
#pragma unroll
      for (int c = 0; c < 4; ++c)
        acc[g] = __builtin_amdgcn_mfma_f32_16x16x32_bf16(afr[g][c], bfr[c], acc[g], 0, 0, 0);
    }

    // select acc[g][r] (r = m&3) via 3 cndmasks per gate
    float pre[4];
#pragma unroll
    for (int g = 0; g < 4; ++g) {
      const float t0v = (r & 1) ? acc[g][1] : acc[g][0];
      const float t1v = (r & 1) ? acc[g][3] : acc[g][2];
      pre[g] = ((r & 2) ? t1v : t0v) + g_c[g];
    }
    const float ig = sigmoid_fast(pre[0]);
    const float fg = sigmoid_fast(pre[1]);
    const float gg = tanh_fast(pre[2]);
    const float og = sigmoid_fast(pre[3]);
    ccur = fmaf(fg, ccur, ig * gg);
    hcur = og * tanh_fast(ccur);
    if (m < 4) hpk[(s + 1) & 1][u] = f2bf(hcur);
    __syncthreads();

#pragma unroll
    for (int g = 0; g < 4; ++g) {
      g_c[g] = g_n[g];
      g_n[g] = g_f[g];
    }
  }

  if (!last) {
    if (m < 4) {
      hstate[(size_t)bc * NH + u] = hcur;
      cstate[(size_t)bc * NH + u] = ccur;
    }
  } else {
    if (m < 4) hf[u] = hcur;
    __syncthreads();
    if (tid < NC) {
      float acc = ld1(fcb + tid);
      const XT* wv = fcw + (size_t)tid * NH;
#pragma unroll
      for (int k = 0; k < NH; ++k) acc = fmaf(ld1(wv + k), hf[k], acc);
      st1(out + (size_t)b * NC + tid, acc);
    }
  }
}

// ---------------------------------------------------------------------------
template <typename XT, typename GXT>
static void run_variant(int want, const int* flag, void* const* d_in, XT* out,
                        GXT* gx, float* hstate, float* cstate, int NBc, int Tc,
                        hipStream_t stream) {
  const XT* X = (const XT*)d_in[0];
  const XT* Wih = (const XT*)d_in[1];
  const XT* Whh = (const XT*)d_in[2];
  const XT* bih = (const XT*)d_in[3];
  const XT* bhh = (const XT*)d_in[4];
  const XT* fcw = (const XT*)d_in[5];
  const XT* fcb = (const XT*)d_in[6];
  const int* lengths = (const int*)d_in[7];
  for (int bb = 0; bb < NB; bb += NBc) {
    for (int tb = 0; tb < NT; tb += Tc) {
      gx_gemm<XT, GXT><<<dim3((NBc * Tc) / 64), dim3(256), 0, stream>>>(
          flag, want, X, Wih, bih, bhh, lengths, gx, bb, tb, Tc);
      lstm_rec<XT, GXT><<<dim3(NBc), dim3(512), 0, stream>>>(
          flag, want, gx, Whh, fcw, fcb, lengths, out, hstate, cstate, bb, tb, Tc);
    }
  }
}

extern "C" void kernel_launch(void* const* d_in, const int* in_sizes, int n_in,
                              void* d_out, int out_size, void* d_ws, size_t ws_size,
                              hipStream_t stream) {
  int* flag = (int*)d_ws;
  detect_dtype<<<dim3(1), dim3(64), 0, stream>>>((const unsigned short*)d_in[0], flag);

  const size_t full_f32 = (size_t)NB * NT * NG * sizeof(float);
  const size_t full_bf16 = (size_t)NB * NT * NG * 2;
  const size_t base = 512;

  int NBc, Tc;
  char* gx_raw;
  float* hstate = (float*)((char*)d_ws + base);
  bool gx_is_f32;

  if (ws_size >= base + full_f32) {
    NBc = NB; Tc = NT; gx_is_f32 = true;
    gx_raw = (char*)d_ws + base;
  } else if (ws_size >= base + full_bf16) {
    NBc = NB; Tc = NT; gx_is_f32 = false;
    gx_raw = (char*)d_ws + base;
  } else {
    Tc = 128; gx_is_f32 = false;
    NBc = 1;
    for (int cand : {64, 16, 4}) {
      size_t need = base + (size_t)cand * NH * 2 * sizeof(float) + (size_t)cand * Tc * NG * 2;
      if (ws_size >= need) { NBc = cand; break; }
    }
    gx_raw = (char*)d_ws + base + (size_t)NBc * NH * 2 * sizeof(float);
  }
  float* cstate = hstate + (size_t)NBc * NH;

  if (gx_is_f32) {
    run_variant<unsigned short, float>(0, flag, d_in, (unsigned short*)d_out,
                                       (float*)gx_raw, hstate, cstate, NBc, Tc, stream);
    run_variant<float, float>(1, flag, d_in, (float*)d_out, (float*)gx_raw, hstate,
                              cstate, NBc, Tc, stream);
  } else {
    run_variant<unsigned short, unsigned short>(0, flag, d_in, (unsigned short*)d_out,
                                                (unsigned short*)gx_raw, hstate, cstate,
                                                NBc, Tc, stream);
    run_variant<float, unsigned short>(1, flag, d_in, (float*)d_out,
                                       (unsigned short*)gx_raw, hstate, cstate, NBc, Tc,
                                       stream);
  }
}

// Round 2
// 583.838 us; speedup vs baseline: 1.0852x; 1.0571x over previous
//
#include <hip/hip_runtime.h>
#include <hip/hip_bf16.h>
#include <stdint.h>
#include <type_traits>

// Problem constants: B=256, T=512, D=300, H=128, 4H=512, C=6
#define NB 256
#define NT 512
#define ND 300
#define NH 128
#define NG 512
#define NC 6

typedef __attribute__((ext_vector_type(8))) short short8;
typedef __attribute__((ext_vector_type(4))) float f32x4;

static __device__ __forceinline__ float bf2f(unsigned int u) {
  return __builtin_bit_cast(float, (u & 0xffffu) << 16);
}
static __device__ __forceinline__ unsigned short f2bf(float f) {
  return __builtin_bit_cast(unsigned short, __float2bfloat16(f));
}
static __device__ __forceinline__ unsigned int packbf(float a, float b) {
  return (unsigned int)f2bf(a) | ((unsigned int)f2bf(b) << 16);
}
static __device__ __forceinline__ float ld1(const unsigned short* p) { return bf2f(*p); }
static __device__ __forceinline__ float ld1(const float* p) { return *p; }
static __device__ __forceinline__ void st1(unsigned short* p, float v) { *p = f2bf(v); }
static __device__ __forceinline__ void st1(float* p, float v) { *p = v; }

static __device__ __forceinline__ float sigmoid_fast(float x) {
  return __builtin_amdgcn_rcpf(1.f + __expf(-x));
}
static __device__ __forceinline__ float tanh_fast(float x) {
  return 1.f - 2.f * __builtin_amdgcn_rcpf(__expf(2.f * x) + 1.f);
}

// Barrier that does NOT drain vmcnt: LDS ordering only. Global-load
// prefetches stay in flight across it (T4 counted-vmcnt idiom); the
// compiler still inserts register-dependency vmcnt waits at first use.
#define BARRIER_LGKM() asm volatile("s_waitcnt lgkmcnt(0)\n\ts_barrier" ::: "memory")

// ---- staging loads: 4 K-elems -> 2 packed bf16 pairs ------------------------
static __device__ __forceinline__ uint2 load4bf_fast(const unsigned short* row, int k) {
  return *(const uint2*)(row + k);  // 8B-aligned (k%4==0, row stride 600B)
}
static __device__ __forceinline__ uint2 load4bf_fast(const float* row, int k) {
  float4 f = *(const float4*)(row + k);  // 16B-aligned (k%4==0, row stride 1200B)
  uint2 v;
  v.x = packbf(f.x, f.y);
  v.y = packbf(f.z, f.w);
  return v;
}
static __device__ __forceinline__ uint2 load4bf(const unsigned short* row, int k, int lim) {
  if (k + 3 < lim) return load4bf_fast(row, k);
  unsigned int e0 = (k + 0 < lim) ? row[k + 0] : 0;
  unsigned int e1 = (k + 1 < lim) ? row[k + 1] : 0;
  unsigned int e2 = (k + 2 < lim) ? row[k + 2] : 0;
  unsigned int e3 = (k + 3 < lim) ? row[k + 3] : 0;
  uint2 v;
  v.x = e0 | (e1 << 16);
  v.y = e2 | (e3 << 16);
  return v;
}
static __device__ __forceinline__ uint2 load4bf(const float* row, int k, int lim) {
  if (k + 3 < lim) return load4bf_fast(row, k);
  float f0 = (k + 0 < lim) ? row[k + 0] : 0.f;
  float f1 = (k + 1 < lim) ? row[k + 1] : 0.f;
  float f2 = (k + 2 < lim) ? row[k + 2] : 0.f;
  float f3 = (k + 3 < lim) ? row[k + 3] : 0.f;
  uint2 v;
  v.x = packbf(f0, f1);
  v.y = packbf(f2, f3);
  return v;
}

// ---------------------------------------------------------------------------
// Dtype detector (flag: 0 = bf16 inputs, 1 = fp32 inputs).
// ---------------------------------------------------------------------------
__global__ void detect_dtype(const unsigned short* __restrict__ X, int* __restrict__ flag) {
  __shared__ int cnt;
  if (threadIdx.x == 0) cnt = 0;
  __syncthreads();
  int c = 0;
  for (int i = threadIdx.x; i < 512; i += 64) {
    unsigned int u = X[i];
    unsigned int e = (u >> 7) & 0xffu;
    if (u == 0u || (e >= 97u && e <= 157u)) c++;
  }
  atomicAdd(&cnt, c);
  __syncthreads();
  if (threadIdx.x == 0) *flag = (cnt >= 448) ? 0 : 1;
}

// ---------------------------------------------------------------------------
// Phase 1: gx[m][n] = sum_k x[b,t,k] * W_ih[n][k]  + (bih[n]+bhh[n]).
//
// M-tile 64, full-K A staged once (As[10][64][40], 50 KB). W streams per
// 32-K chunk. THIS ROUND: (a) all in-loop barriers are lgkmcnt-only (no
// vmcnt(0) drain -> W prefetch loads float across barriers), (b) 3-slot
// register prefetch (distance 3: load chunk kc+3 at chunk kc, LDS-write at
// kc+2 -> ~2 chunk bodies of latency slack), (c) W staging remapped to
// 8 lanes/row: each instruction covers 128 B contiguous per row (was 32 B
// scattered), (d) next pass's chunks 0-2 preloaded at pass end.
// ---------------------------------------------------------------------------
template <typename XT, typename GXT>
__global__ __launch_bounds__(256) void gx_gemm(const int* __restrict__ flag, int want,
                                               const XT* __restrict__ X,
                                               const XT* __restrict__ Wih,
                                               const XT* __restrict__ bih,
                                               const XT* __restrict__ bhh,
                                               const int* __restrict__ lengths,
                                               GXT* __restrict__ gx,
                                               int b_base, int t_base, int Tc) {
  if (*flag != want) return;
  const int mb = blockIdx.x;
  const int m0 = mb << 6;  // 64 rows per block
  const int bc = m0 / Tc;
  const int trel0 = m0 % Tc;
  const int b = b_base + bc;
  const int t0 = t_base + trel0;
  const int len = lengths[b];
  if (t0 >= len) return;

  __shared__ unsigned short As[10][64][40];  // 50 KB, staged once
  __shared__ unsigned short Bs[2][128][40];  // 20 KB, double-buffered

  const int tid = threadIdx.x;
  const int lane = tid & 63;
  const int wave = tid >> 6;
  const int wm = wave & 1;   // M strip of 32
  const int wn = wave >> 1;  // N strip of 64 (within 128-col pass)
  const int lq = lane >> 4;
  const int lr = lane & 15;

  // ---- Prologue: stage A (64 rows x 320 k) once --------------------------
  const int rA = tid >> 2;
  const int cA = (tid & 3) << 2;  // 0,4,8,12
  const XT* xrow = X + ((size_t)b * NT + t0 + rA) * ND;
  {
    uint2 a0[10], a1[10];
#pragma unroll
    for (int kc = 0; kc < 9; ++kc) {
      a0[kc] = load4bf_fast(xrow, kc * 32 + cA);
      a1[kc] = load4bf_fast(xrow, kc * 32 + 16 + cA);
    }
    a0[9] = load4bf(xrow, 288 + cA, ND);       // 288..303 masked at 300
    a1[9] = load4bf(xrow, 288 + 16 + cA, ND);  // 304..319 all masked
#pragma unroll
    for (int kc = 0; kc < 10; ++kc) {
      *(uint2*)&As[kc][rA][cA] = a0[kc];
      *(uint2*)&As[kc][rA][16 + cA] = a1[kc];
    }
  }

  // ---- W stream: 8 lanes per row (coalesced 128B/row segments) -----------
  const int rb = tid >> 3;  // 0..31; thread covers rows rb+32j, j=0..3
  const int kq = tid & 7;   // k offset kq*4 within the 32-k chunk

  // 3-slot register prefetch: chunk m of current pass lives in bv[m%3].
  uint2 bv[3][4];
  {
    const XT* wb = Wih + (size_t)rb * ND;  // pass 0 (n0 = 0)
#pragma unroll
    for (int s3 = 0; s3 < 3; ++s3)
#pragma unroll
      for (int j = 0; j < 4; ++j)
        bv[s3][j] = load4bf_fast(wb + (size_t)(32 * j) * ND, s3 * 32 + kq * 4);
  }

  for (int nt = 0; nt < 4; ++nt) {
    const int n0 = nt << 7;
    const XT* wb = Wih + (size_t)(n0 + rb) * ND;

    f32x4 acc[2][4];
#pragma unroll
    for (int i = 0; i < 2; ++i)
#pragma unroll
      for (int j = 0; j < 4; ++j) {
        f32x4 z = {0.f, 0.f, 0.f, 0.f};
        acc[i][j] = z;
      }

    // write chunk 0 (Bs[0] readers of prev pass finished at its kc=8 barrier;
    // at nt=0 the barrier below also publishes the A staging)
#pragma unroll
    for (int j = 0; j < 4; ++j) *(uint2*)&Bs[0][rb + 32 * j][kq * 4] = bv[0][j];
    BARRIER_LGKM();

#pragma unroll
    for (int kc = 0; kc < 10; ++kc) {
      const int bi = kc & 1;
      // stage chunk kc+1 (loaded at chunk kc-2 -> ~2 bodies of slack)
      if (kc < 9) {
#pragma unroll
        for (int j = 0; j < 4; ++j)
          *(uint2*)&Bs[bi ^ 1][rb + 32 * j][kq * 4] = bv[(kc + 1) % 3][j];
      }
      // prefetch chunk kc+3 into the slot freed by chunk kc's LDS-write
      if (kc < 7) {
        const int kn = (kc + 3) * 32 + kq * 4;
        if (kc < 6) {
#pragma unroll
          for (int j = 0; j < 4; ++j)
            bv[kc % 3][j] = load4bf_fast(wb + (size_t)(32 * j) * ND, kn);
        } else {  // chunk 9: k 288..319 masked at 300
#pragma unroll
          for (int j = 0; j < 4; ++j)
            bv[kc % 3][j] = load4bf(wb + (size_t)(32 * j) * ND, kn, ND);
        }
      }

      short8 af[2], bq[4];
#pragma unroll
      for (int tm = 0; tm < 2; ++tm)
        af[tm] = *(const short8*)&As[kc][wm * 32 + tm * 16 + lr][lq * 8];
#pragma unroll
      for (int tn = 0; tn < 4; ++tn)
        bq[tn] = *(const short8*)&Bs[bi][wn * 64 + tn * 16 + lr][lq * 8];
#pragma unroll
      for (int tm = 0; tm < 2; ++tm)
#pragma unroll
        for (int tn = 0; tn < 4; ++tn)
          acc[tm][tn] =
              __builtin_amdgcn_mfma_f32_16x16x32_bf16(af[tm], bq[tn], acc[tm][tn], 0, 0, 0);
      BARRIER_LGKM();
    }

    // preload next pass's chunks 0-2 (slots all free after kc=8's write);
    // consumed at next pass top / kc=0,1 -> epilogue hides the latency
    if (nt < 3) {
      const XT* wb2 = Wih + (size_t)((nt + 1) * 128 + rb) * ND;
#pragma unroll
      for (int s3 = 0; s3 < 3; ++s3)
#pragma unroll
        for (int j = 0; j < 4; ++j)
          bv[s3][j] = load4bf_fast(wb2 + (size_t)(32 * j) * ND, s3 * 32 + kq * 4);
    }

    // Epilogue: add bias (bih+bhh) per output column, store.
    // C/D layout: col = lane&15, row = (lane>>4)*4 + reg
    float bias_c[4];
#pragma unroll
    for (int tn = 0; tn < 4; ++tn) {
      const int col = n0 + wn * 64 + tn * 16 + lr;
      bias_c[tn] = ld1(bih + col) + ld1(bhh + col);
    }
#pragma unroll
    for (int tm = 0; tm < 2; ++tm)
#pragma unroll
      for (int tn = 0; tn < 4; ++tn)
#pragma unroll
        for (int rg = 0; rg < 4; ++rg) {
          const int row = wm * 32 + tm * 16 + lq * 4 + rg;
          if (t0 + row < len) {
            const int col = n0 + wn * 64 + tn * 16 + lr;
            st1(gx + (size_t)(m0 + row) * NG + col, acc[tm][tn][rg] + bias_c[tn]);
          }
        }
  }
}

// ---------------------------------------------------------------------------
// Phase 2: per-batch recurrence via MFMA matvec. 8 waves; wave w owns units
// [16w,16w+16). THIS ROUND: (a) per-step barrier is lgkmcnt-only -- the old
// __syncthreads drained vmcnt(0), forcing every step to eat the full
// L3-latency of its own gx prefetch (the ~600 unexplained cycles of the
// 1300-cycle step); (b) gx prefetch uses static-parity slots gs0/gs1 with
// the loop unrolled by 2, so the load issued at step s is first waited on
// at step s+2 (true distance-2). Arithmetic is bit-identical to round 1
// (same MFMA order, same gate math) -- absmax must stay 0.001953125.
// ---------------------------------------------------------------------------
template <typename XT, typename GXT>
__global__ __launch_bounds__(512)
__attribute__((amdgpu_waves_per_eu(2, 2)))
void lstm_rec(const int* __restrict__ flag, int want,
              const GXT* __restrict__ gx,
              const XT* __restrict__ Whh,
              const XT* __restrict__ fcw,
              const XT* __restrict__ fcb,
              const int* __restrict__ lengths,
              XT* __restrict__ out,
              float* __restrict__ hstate,
              float* __restrict__ cstate,
              int b_base, int t_base, int Tc) {
  if (*flag != want) return;
  const int bc = blockIdx.x;
  const int b = b_base + bc;
  int len = lengths[b];
  if (len > NT) len = NT;
  if (len < 0) len = 0;
  const bool first = (t_base == 0);
  const bool last = (t_base + Tc >= NT);
  const int tend = (len < t_base + Tc) ? len : (t_base + Tc);
  if (!last && tend <= t_base) return;  // no steps; ws state untouched
  int nsteps = tend - t_base;
  if (nsteps < 0) nsteps = 0;

  const int tid = threadIdx.x;
  const int w8 = tid >> 6;         // wave: units [w8*16, w8*16+16)
  const int l = tid & 63;
  const int q = l >> 4;            // quad group
  const int m = l & 15;            // A-frag row select / D column id
  const int u0 = w8 * 16 + q * 4;  // first unit of this lane's D rows
  const int r = m & 3;             // unit handled by this lane
  const int u = u0 + r;

  __shared__ __align__(16) unsigned short hpk[2][NH];  // packed bf16 h, dbuf
  __shared__ __align__(16) float hf[NH];               // final h (FC epilogue)

  // A fragments: afr[g][c] = W_hh[g*128 + w8*16 + m][c*32 + q*8 .. +8]
  short8 afr[4][4];
#pragma unroll
  for (int g = 0; g < 4; ++g) {
    const int row = g * NH + w8 * 16 + m;
    if constexpr (std::is_same_v<XT, unsigned short>) {
#pragma unroll
      for (int c = 0; c < 4; ++c)
        afr[g][c] = *(const short8*)(Whh + (size_t)row * NH + c * 32 + q * 8);
    } else {
#pragma unroll
      for (int c = 0; c < 4; ++c) {
        const float* p = Whh + (size_t)row * NH + c * 32 + q * 8;
        float4 f0 = *(const float4*)p;
        float4 f1 = *(const float4*)(p + 4);
        union { unsigned int uu[4]; short8 s; } cv2;
        cv2.uu[0] = packbf(f0.x, f0.y);
        cv2.uu[1] = packbf(f0.z, f0.w);
        cv2.uu[2] = packbf(f1.x, f1.y);
        cv2.uu[3] = packbf(f1.z, f1.w);
        afr[g][c] = cv2.s;
      }
    }
  }

  float hcur = 0.f, ccur = 0.f;
  if (!first) {
    hcur = hstate[(size_t)bc * NH + u];
    ccur = cstate[(size_t)bc * NH + u];
  }
  if (m < 4) hpk[0][u] = f2bf(hcur);
  __syncthreads();

  // gx pointers for this lane's unit: 4 gates at offsets g*128
  const GXT* gp = gx + (size_t)bc * Tc * NG + u;
  const int lastidx = (nsteps > 0) ? nsteps - 1 : 0;

  // static-parity prefetch slots: gs0 = even steps, gs1 = odd steps
  float gs0[4], gs1[4];
  {
    const int i1 = (1 < lastidx) ? 1 : lastidx;
#pragma unroll
    for (int g = 0; g < 4; ++g) {
      gs0[g] = ld1(gp + g * NH);
      gs1[g] = ld1(gp + (size_t)i1 * NG + g * NH);
    }
  }

  // One LSTM step. PAR is a compile-time 0/1: read hpk[PAR], write hpk[PAR^1].
  // GC (the gate slot) is consumed, then immediately reloaded with step S+2's
  // gx row -- the vmcnt wait for that load lands 2 steps later.
#define REC_STEP(S, PAR, GC)                                                         \
  {                                                                                  \
    short8 bfr[4];                                                                   \
    const unsigned short* hrow = hpk[(PAR)];                                         \
    _Pragma("unroll") for (int c = 0; c < 4; ++c)                                    \
        bfr[c] = *(const short8*)&hrow[c * 32 + q * 8];                              \
    f32x4 acc[4];                                                                    \
    _Pragma("unroll") for (int g = 0; g < 4; ++g) {                                  \
      f32x4 z = {0.f, 0.f, 0.f, 0.f};                                                \
      acc[g] = z;                                                                    \
      _Pragma("unroll") for (int c = 0; c < 4; ++c)                                  \
          acc[g] = __builtin_amdgcn_mfma_f32_16x16x32_bf16(afr[g][c], bfr[c],        \
                                                           acc[g], 0, 0, 0);         \
    }                                                                                \
    float pre[4];                                                                    \
    _Pragma("unroll") for (int g = 0; g < 4; ++g) {                                  \
      const float t0v = (r & 1) ? acc[g][1] : acc[g][0];                             \
      const float t1v = (r & 1) ? acc[g][3] : acc[g][2];                             \
      pre[g] = ((r & 2) ? t1v : t0v) + GC[g];                                        \
    }                                                                                \
    {                                                                                \
      int idx_ = (S) + 2;                                                            \
      if (idx_ > lastidx) idx_ = lastidx;                                            \
      _Pragma("unroll") for (int g = 0; g < 4; ++g)                                  \
          GC[g] = ld1(gp + (size_t)idx_ * NG + g * NH);                              \
    }                                                                                \
    const float ig = sigmoid_fast(pre[0]);                                           \
    const float fg = sigmoid_fast(pre[1]);                                           \
    const float gg = tanh_fast(pre[2]);                                              \
    const float og = sigmoid_fast(pre[3]);                                           \
    ccur = fmaf(fg, ccur, ig * gg);                                                  \
    hcur = og * tanh_fast(ccur);                                                     \
    if (m < 4) hpk[(PAR) ^ 1][u] = f2bf(hcur);                                       \
    BARRIER_LGKM();                                                                  \
  }

  int s = 0;
  for (; s + 1 < nsteps; s += 2) {
    REC_STEP(s, 0, gs0);
    REC_STEP(s + 1, 1, gs1);
  }
  if (s < nsteps) {
    REC_STEP(s, 0, gs0);
  }
#undef REC_STEP

  if (!last) {
    if (m < 4) {
      hstate[(size_t)bc * NH + u] = hcur;
      cstate[(size_t)bc * NH + u] = ccur;
    }
  } else {
    if (m < 4) hf[u] = hcur;
    __syncthreads();
    if (tid < NC) {
      float acc = ld1(fcb + tid);
      const XT* wv = fcw + (size_t)tid * NH;
#pragma unroll
      for (int k = 0; k < NH; ++k) acc = fmaf(ld1(wv + k), hf[k], acc);
      st1(out + (size_t)b * NC + tid, acc);
    }
  }
}

// ---------------------------------------------------------------------------
template <typename XT, typename GXT>
static void run_variant(int want, const int* flag, void* const* d_in, XT* out,
                        GXT* gx, float* hstate, float* cstate, int NBc, int Tc,
                        hipStream_t stream) {
  const XT* X = (const XT*)d_in[0];
  const XT* Wih = (const XT*)d_in[1];
  const XT* Whh = (const XT*)d_in[2];
  const XT* bih = (const XT*)d_in[3];
  const XT* bhh = (const XT*)d_in[4];
  const XT* fcw = (const XT*)d_in[5];
  const XT* fcb = (const XT*)d_in[6];
  const int* lengths = (const int*)d_in[7];
  for (int bb = 0; bb < NB; bb += NBc) {
    for (int tb = 0; tb < NT; tb += Tc) {
      gx_gemm<XT, GXT><<<dim3((NBc * Tc) / 64), dim3(256), 0, stream>>>(
          flag, want, X, Wih, bih, bhh, lengths, gx, bb, tb, Tc);
      lstm_rec<XT, GXT><<<dim3(NBc), dim3(512), 0, stream>>>(
          flag, want, gx, Whh, fcw, fcb, lengths, out, hstate, cstate, bb, tb, Tc);
    }
  }
}

extern "C" void kernel_launch(void* const* d_in, const int* in_sizes, int n_in,
                              void* d_out, int out_size, void* d_ws, size_t ws_size,
                              hipStream_t stream) {
  int* flag = (int*)d_ws;
  detect_dtype<<<dim3(1), dim3(64), 0, stream>>>((const unsigned short*)d_in[0], flag);

  const size_t full_f32 = (size_t)NB * NT * NG * sizeof(float);
  const size_t full_bf16 = (size_t)NB * NT * NG * 2;
  const size_t base = 512;

  int NBc, Tc;
  char* gx_raw;
  float* hstate = (float*)((char*)d_ws + base);
  bool gx_is_f32;

  if (ws_size >= base + full_f32) {
    NBc = NB; Tc = NT; gx_is_f32 = true;
    gx_raw = (char*)d_ws + base;
  } else if (ws_size >= base + full_bf16) {
    NBc = NB; Tc = NT; gx_is_f32 = false;
    gx_raw = (char*)d_ws + base;
  } else {
    Tc = 128; gx_is_f32 = false;
    NBc = 1;
    for (int cand : {64, 16, 4}) {
      size_t need = base + (size_t)cand * NH * 2 * sizeof(float) + (size_t)cand * Tc * NG * 2;
      if (ws_size >= need) { NBc = cand; break; }
    }
    gx_raw = (char*)d_ws + base + (size_t)NBc * NH * 2 * sizeof(float);
  }
  float* cstate = hstate + (size_t)NBc * NH;

  if (gx_is_f32) {
    run_variant<unsigned short, float>(0, flag, d_in, (unsigned short*)d_out,
                                       (float*)gx_raw, hstate, cstate, NBc, Tc, stream);
    run_variant<float, float>(1, flag, d_in, (float*)d_out, (float*)gx_raw, hstate,
                              cstate, NBc, Tc, stream);
  } else {
    run_variant<unsigned short, unsigned short>(0, flag, d_in, (unsigned short*)d_out,
                                                (unsigned short*)gx_raw, hstate, cstate,
                                                NBc, Tc, stream);
    run_variant<float, unsigned short>(1, flag, d_in, (float*)d_out,
                                       (unsigned short*)gx_raw, hstate, cstate, NBc, Tc,
                                       stream);
  }
}